// Round 12
// baseline (204.851 us; speedup 1.0000x reference)
//
#include <hip/hip_runtime.h>
#include <math.h>

#define D_MODEL 1024
#define N_HEADS 16
#define D_HEAD  64
#define B_SZ    2
#define T_SEQ   2048

typedef short bf16x8 __attribute__((ext_vector_type(8)));
typedef short bf16x4 __attribute__((ext_vector_type(4)));
typedef float f32x4  __attribute__((ext_vector_type(4)));
typedef unsigned short us4 __attribute__((ext_vector_type(4)));

// fp32 -> bf16 (RNE)
__device__ __forceinline__ unsigned short f2bf(float f) {
  union { float f; unsigned u; } v; v.f = f;
  unsigned r = v.u + 0x7FFFu + ((v.u >> 16) & 1u);
  return (unsigned short)(r >> 16);
}
// bf16 -> fp32
__device__ __forceinline__ float bf2f(unsigned short s) {
  union { unsigned u; float f; } v; v.u = ((unsigned)s) << 16;
  return v.f;
}
// pack two fp32 -> bf16x2 (RTZ) in one v_perm_b32
__device__ __forceinline__ unsigned pack2_rtz(float lo, float hi) {
  union { float f; unsigned u; } a, b; a.f = hi; b.f = lo;
  return __builtin_amdgcn_perm(a.u, b.u, 0x07060302u);
}

// async global->LDS, 16B per lane. LDS dest = wave-uniform base + lane*16.
__device__ __forceinline__ void async_copy16(const unsigned short* g, unsigned short* l) {
  __builtin_amdgcn_global_load_lds(
      (__attribute__((address_space(1))) void*)(g),
      (__attribute__((address_space(3))) void*)(l), 16, 0, 0);
}

// Work table for flash_part: value = g | piece<<4 | npieces<<6, ordered
// longest-piece-first (LPT). direct g0-3; 2-way g4-11; 3-way g12-15.
__device__ const unsigned short FLASH_TBL[32] = {
  (unsigned short)(11| (0<<4) | (2<<6)), (unsigned short)(11 | (1<<4) | (2<<6)),
  (unsigned short)(15 | (0<<4) | (3<<6)), (unsigned short)(15 | (1<<4) | (3<<6)),
  (unsigned short)(15 | (2<<4) | (3<<6)),
  (unsigned short)(10 | (0<<4) | (2<<6)), (unsigned short)(10 | (1<<4) | (2<<6)),
  (unsigned short)(14 | (0<<4) | (3<<6)), (unsigned short)(14 | (1<<4) | (3<<6)),
  (unsigned short)(14 | (2<<4) | (3<<6)),
  (unsigned short)(9  | (0<<4) | (2<<6)), (unsigned short)(9  | (1<<4) | (2<<6)),
  (unsigned short)(13 | (0<<4) | (3<<6)), (unsigned short)(13 | (1<<4) | (3<<6)),
  (unsigned short)(13 | (2<<4) | (3<<6)),
  (unsigned short)(12 | (0<<4) | (3<<6)), (unsigned short)(12 | (1<<4) | (3<<6)),
  (unsigned short)(12 | (2<<4) | (3<<6)),
  (unsigned short)(8  | (0<<4) | (2<<6)), (unsigned short)(8  | (1<<4) | (2<<6)),
  (unsigned short)(3  | (0<<4) | (1<<6)),
  (unsigned short)(7  | (0<<4) | (2<<6)), (unsigned short)(7  | (1<<4) | (2<<6)),
  (unsigned short)(6  | (0<<4) | (2<<6)), (unsigned short)(6  | (1<<4) | (2<<6)),
  (unsigned short)(2  | (0<<4) | (1<<6)),
  (unsigned short)(5  | (0<<4) | (2<<6)), (unsigned short)(5  | (1<<4) | (2<<6)),
  (unsigned short)(4  | (0<<4) | (2<<6)), (unsigned short)(4  | (1<<4) | (2<<6)),
  (unsigned short)(1  | (0<<4) | (1<<6)), (unsigned short)(0  | (0<<4) | (1<<6)),
};

// ---------------------------------------------------------------------------
// Fused converts. grid (32,32,8): z<4 -> W[z] fp32[K,N] -> wt bf16 [N,K] at
// slot (z+1)&3 (layout: [wo, wq, wk, wv]); z>=4 -> x fp32 -> bf16.
// ---------------------------------------------------------------------------
__global__ __launch_bounds__(256) void conv_all(
    const float* __restrict__ x,
    const float* __restrict__ wq, const float* __restrict__ wk,
    const float* __restrict__ wv, const float* __restrict__ wo,
    unsigned short* __restrict__ wt, unsigned short* __restrict__ xb)
{
  const int z = blockIdx.z;
  if (z < 4) {
    const float* W = (z == 0) ? wq : (z == 1) ? wk : (z == 2) ? wv : wo;
    unsigned short* O = wt + (size_t)((z + 1) & 3) * D_MODEL * D_MODEL;
    __shared__ float t[32][33];
    const int tx = threadIdx.x & 31, ty = threadIdx.x >> 5;
    const int kb = blockIdx.x * 32, nb = blockIdx.y * 32;
    #pragma unroll
    for (int i = 0; i < 4; i++)
      t[ty + i * 8][tx] = W[(size_t)(kb + ty + i * 8) * D_MODEL + nb + tx];
    __syncthreads();
    #pragma unroll
    for (int i = 0; i < 4; i++)
      O[(size_t)(nb + ty + i * 8) * D_MODEL + kb + tx] = f2bf(t[tx][ty + i * 8]);
  } else {
    const int row = (z - 4) * 1024 + blockIdx.y * 32 + (threadIdx.x >> 3);
    const int col = blockIdx.x * 32 + (threadIdx.x & 7) * 4;
    float4 v = *(const float4*)&x[(size_t)row * D_MODEL + col];
    us4 o = { f2bf(v.x), f2bf(v.y), f2bf(v.z), f2bf(v.w) };
    *(us4*)&xb[(size_t)row * D_MODEL + col] = o;
  }
}

// ---------------------------------------------------------------------------
// Fused QKV GEMM, 128(token) x 64(feature) tiles, grid (32,48) = 1536 blocks.
// Bt points at [wq,wk,wv] (wt + WN). q/k: operands swapped; v -> vT.
// ---------------------------------------------------------------------------
#define BKg 64

__global__ __launch_bounds__(256) void qkv_gemm(
    const unsigned short* __restrict__ A, const unsigned short* __restrict__ Bt,
    const float* __restrict__ bq, const float* __restrict__ bk,
    const float* __restrict__ bv, unsigned short* __restrict__ qkv,
    unsigned short* __restrict__ vT)
{
  __shared__ unsigned short As[128 * BKg];   // x tile: 16 KB
  __shared__ unsigned short Bs[64 * BKg];    // w tile:  8 KB

  const int tid  = threadIdx.x;
  const int wv   = tid >> 6;
  const int lane = tid & 63;
  const int lr   = lane & 15;
  const int quad = lane >> 4;
  const int wm   = wv >> 1;
  const int wn   = wv & 1;
  const int row0 = blockIdx.x * 128;   // tokens
  const int col0 = blockIdx.y * 64;    // feature col in [0,3072)
  const int K = D_MODEL;

  const int mid = col0 >> 10;                       // 0=q,1=k,2=v
  const float* bias = (mid == 0) ? bq : (mid == 1) ? bk : bv;

  f32x4 acc[8];
  #pragma unroll
  for (int i = 0; i < 8; i++) acc[i] = (f32x4){0.f, 0.f, 0.f, 0.f};

  for (int k0 = 0; k0 < K; k0 += BKg) {
    #pragma unroll
    for (int it = 0; it < 4; it++) {
      const int gg = wv * 256 + it * 64 + lane;
      const int r  = gg >> 3;
      const int gc = ((gg & 7) ^ (r & 7)) * 8;
      async_copy16(A + (size_t)(row0 + r) * K + k0 + gc,
                   (unsigned short*)As + (size_t)(wv * 256 + it * 64) * 8);
    }
    #pragma unroll
    for (int it = 0; it < 2; it++) {
      const int gg = wv * 128 + it * 64 + lane;
      const int r  = gg >> 3;
      const int gc = ((gg & 7) ^ (r & 7)) * 8;
      async_copy16(Bt + (size_t)(col0 + r) * K + k0 + gc,
                   (unsigned short*)Bs + (size_t)(wv * 128 + it * 64) * 8);
    }
    __syncthreads();

    if (mid == 2) {
      bf16x8 aF[4][2], bF[2][2];
      #pragma unroll
      for (int hf = 0; hf < 2; hf++) {
        const int kc = (hf * 4 + quad) ^ (lr & 7);
        #pragma unroll
        for (int mi = 0; mi < 4; mi++)
          aF[mi][hf] = *(const bf16x8*)&As[(wm * 64 + mi * 16 + lr) * BKg + kc * 8];
        #pragma unroll
        for (int ni = 0; ni < 2; ni++)
          bF[ni][hf] = *(const bf16x8*)&Bs[(wn * 32 + ni * 16 + lr) * BKg + kc * 8];
      }
      #pragma unroll
      for (int hf = 0; hf < 2; hf++)
        #pragma unroll
        for (int mi = 0; mi < 4; mi++)
          #pragma unroll
          for (int ni = 0; ni < 2; ni++)
            acc[mi * 2 + ni] = __builtin_amdgcn_mfma_f32_16x16x32_bf16(
                aF[mi][hf], bF[ni][hf], acc[mi * 2 + ni], 0, 0, 0);
    } else {
      bf16x8 aF[2][2], bF[4][2];
      #pragma unroll
      for (int hf = 0; hf < 2; hf++) {
        const int kc = (hf * 4 + quad) ^ (lr & 7);
        #pragma unroll
        for (int mi = 0; mi < 2; mi++)
          aF[mi][hf] = *(const bf16x8*)&Bs[(wm * 32 + mi * 16 + lr) * BKg + kc * 8];
        #pragma unroll
        for (int ni = 0; ni < 4; ni++)
          bF[ni][hf] = *(const bf16x8*)&As[(wn * 64 + ni * 16 + lr) * BKg + kc * 8];
      }
      #pragma unroll
      for (int hf = 0; hf < 2; hf++)
        #pragma unroll
        for (int mi = 0; mi < 2; mi++)
          #pragma unroll
          for (int ni = 0; ni < 4; ni++)
            acc[mi * 4 + ni] = __builtin_amdgcn_mfma_f32_16x16x32_bf16(
                aF[mi][hf], bF[ni][hf], acc[mi * 4 + ni], 0, 0, 0);
    }
    __syncthreads();
  }

  if (mid == 2) {
    #pragma unroll
    for (int ni = 0; ni < 2; ni++) {
      const int nn = (col0 & 1023) + wn * 32 + ni * 16 + lr;
      const float bv_ = bias[nn];
      const int h = nn >> 6, d = nn & 63;
      #pragma unroll
      for (int mi = 0; mi < 4; mi++) {
        const int t0_ = row0 + wm * 64 + mi * 16 + quad * 4;
        const int b = t0_ >> 11, tl = t0_ & 2047;
        us4 o;
        #pragma unroll
        for (int i = 0; i < 4; i++) o[i] = f2bf(acc[mi * 2 + ni][i] + bv_);
        *(us4*)&vT[((size_t)(b * N_HEADS + h) * D_HEAD + d) * T_SEQ + tl] = o;
      }
    }
  } else {
    unsigned short* dst = qkv + (size_t)mid * (4096u * 1024u);
    #pragma unroll
    for (int ni = 0; ni < 4; ni++) {
      const int t = row0 + wn * 64 + ni * 16 + lr;
      const int b = t >> 11, tl = t & 2047;
      #pragma unroll
      for (int mi = 0; mi < 2; mi++) {
        const int f = (col0 & 1023) + wm * 32 + mi * 16 + quad * 4;
        const int h = f >> 6, d = f & 63;
        const float4 b4 = *(const float4*)&bias[f];
        us4 o;
        o[0] = f2bf(acc[mi * 4 + ni][0] + b4.x);
        o[1] = f2bf(acc[mi * 4 + ni][1] + b4.y);
        o[2] = f2bf(acc[mi * 4 + ni][2] + b4.z);
        o[3] = f2bf(acc[mi * 4 + ni][3] + b4.w);
        *(us4*)&dst[((size_t)(b * N_HEADS + h) * T_SEQ + tl) * D_HEAD + d] = o;
      }
    }
  }
}

// ---------------------------------------------------------------------------
// bf16 MFMA GEMM (O-projection): C = A[M,K] @ Wt[N,K]^T + bias[N], fp32 out.
// 128x64 tile -> grid (32,16) = 512 blocks.
// ---------------------------------------------------------------------------
__global__ __launch_bounds__(256) void mfma_gemm(
    const unsigned short* __restrict__ A, const unsigned short* __restrict__ Bt,
    const float* __restrict__ bias, float* __restrict__ C,
    int M, int N, int K)
{
  __shared__ unsigned short As[128 * BKg];
  __shared__ unsigned short Bs[64 * BKg];

  const int tid  = threadIdx.x;
  const int wv   = tid >> 6;
  const int lane = tid & 63;
  const int lr   = lane & 15;
  const int quad = lane >> 4;
  const int wm   = wv >> 1;
  const int wn   = wv & 1;
  const int row0 = blockIdx.x * 128;
  const int col0 = blockIdx.y * 64;

  f32x4 acc[4][2];
  #pragma unroll
  for (int mi = 0; mi < 4; mi++)
    #pragma unroll
    for (int ni = 0; ni < 2; ni++) acc[mi][ni] = (f32x4){0.f, 0.f, 0.f, 0.f};

  for (int k0 = 0; k0 < K; k0 += BKg) {
    #pragma unroll
    for (int it = 0; it < 4; it++) {
      const int gg = wv * 256 + it * 64 + lane;
      const int r  = gg >> 3;
      const int gc = ((gg & 7) ^ (r & 7)) * 8;
      async_copy16(A + (size_t)(row0 + r) * K + k0 + gc,
                   (unsigned short*)As + (size_t)(wv * 256 + it * 64) * 8);
    }
    #pragma unroll
    for (int it = 0; it < 2; it++) {
      const int gg = wv * 128 + it * 64 + lane;
      const int r  = gg >> 3;
      const int gc = ((gg & 7) ^ (r & 7)) * 8;
      async_copy16(Bt + (size_t)(col0 + r) * K + k0 + gc,
                   (unsigned short*)Bs + (size_t)(wv * 128 + it * 64) * 8);
    }
    __syncthreads();

    bf16x8 aF[4][2], bF[2][2];
    #pragma unroll
    for (int hf = 0; hf < 2; hf++) {
      const int kc = (hf * 4 + quad) ^ (lr & 7);
      #pragma unroll
      for (int mi = 0; mi < 4; mi++)
        aF[mi][hf] = *(const bf16x8*)&As[(wm * 64 + mi * 16 + lr) * BKg + kc * 8];
      #pragma unroll
      for (int ni = 0; ni < 2; ni++)
        bF[ni][hf] = *(const bf16x8*)&Bs[(wn * 32 + ni * 16 + lr) * BKg + kc * 8];
    }
    #pragma unroll
    for (int hf = 0; hf < 2; hf++)
      #pragma unroll
      for (int mi = 0; mi < 4; mi++)
        #pragma unroll
        for (int ni = 0; ni < 2; ni++)
          acc[mi][ni] = __builtin_amdgcn_mfma_f32_16x16x32_bf16(
              aF[mi][hf], bF[ni][hf], acc[mi][ni], 0, 0, 0);
    __syncthreads();
  }

  #pragma unroll
  for (int ni = 0; ni < 2; ni++) {
    const int n = col0 + wn * 32 + ni * 16 + lr;
    const float bv = bias[n];
    #pragma unroll
    for (int mi = 0; mi < 4; mi++) {
      #pragma unroll
      for (int i = 0; i < 4; i++) {
        const int m = row0 + wm * 64 + mi * 16 + quad * 4 + i;
        C[(size_t)m * N + n] = acc[mi][ni][i] + bv;
      }
    }
  }
}

// ---------------------------------------------------------------------------
// LDS-staged S^T flash attention, FIXED-MAX softmax (causal), table-split.
// Block = 4 waves on one bh; wave w: qg = 4g + w (32 Q rows). Work item y
// decoded via FLASH_TBL: (g, piece, npieces). Partial slots (per bh, 112):
// g4-11 2-way -> (qg-16)*2+piece; g12-15 3-way -> 64+(qg-48)*3+piece.
// ---------------------------------------------------------------------------
__global__ __launch_bounds__(256) void flash_part(
    const unsigned short* __restrict__ Q, const unsigned short* __restrict__ K,
    const unsigned short* __restrict__ Vt, unsigned short* __restrict__ Out,
    unsigned short* __restrict__ Opart, float* __restrict__ Lpart)
{
  const int bh = blockIdx.x;              // 0..31
  const unsigned tv = FLASH_TBL[blockIdx.y];
  const int g     = tv & 15;
  const int piece = (tv >> 4) & 3;
  const int np    = tv >> 6;

  const int b  = bh >> 4;
  const int h  = bh & 15;

  const unsigned short* Qb = Q  + (size_t)bh * T_SEQ * D_HEAD;
  const unsigned short* Kb = K  + (size_t)bh * T_SEQ * D_HEAD;
  const unsigned short* Vb = Vt + (size_t)bh * D_HEAD * T_SEQ;   // [d][t]

  __shared__ __align__(16) unsigned short Ks[2][64 * 64];
  __shared__ __align__(16) unsigned short Vs[2][64 * 64];

  const int tid  = threadIdx.x;
  const int wv4  = tid >> 6;
  const int lane = tid & 63;
  const int lr   = lane & 15;
  const int quad = lane >> 4;

  const int qg      = 4 * g + wv4;
  const int q0      = qg * 32;
  const int my_full = (qg >> 1) + 1;       // true last tile + 1
  const int ntot    = 2 * g + 2;

  int lo, hi;
  if (np == 1)      { lo = 0; hi = ntot; }
  else if (np == 2) { lo = piece ? (g + 1) : 0; hi = piece ? ntot : (g + 1); }
  else {
    const int a3 = ntot / 3, b3 = (2 * ntot) / 3;
    lo = (piece == 0) ? 0 : (piece == 1) ? a3 : b3;
    hi = (piece == 0) ? a3 : (piece == 1) ? b3 : ntot;
  }
  const int tstart = lo;
  const int bend   = hi;                                   // block staging range
  const int my_end = (hi < my_full) ? hi : my_full;        // wave compute range

  const int cbase = (tid & ~63);
  auto stage = [&](int buf, int tile) {
    const unsigned short* ksrc = Kb + (size_t)tile * 64 * D_HEAD;
    const int kv0 = tile * 64;
    #pragma unroll
    for (int it = 0; it < 2; it++) {
      const int gg = it * 256 + tid;
      const int r  = gg >> 3;
      const int gc = (gg & 7) ^ (r & 7);
      async_copy16(ksrc + r * 64 + gc * 8, &Ks[buf][(size_t)(it * 256 + cbase) * 8]);
      async_copy16(Vb + (size_t)r * T_SEQ + kv0 + gc * 8, &Vs[buf][(size_t)(it * 256 + cbase) * 8]);
    }
  };

  // Q as B-operand (loop-invariant)
  bf16x8 bQ[2][2];
  #pragma unroll
  for (int qb = 0; qb < 2; qb++)
    #pragma unroll
    for (int kh = 0; kh < 2; kh++)
      bQ[qb][kh] = *(const bf16x8*)&Qb[(size_t)(q0 + qb * 16 + lr) * D_HEAD + kh * 32 + quad * 8];

  f32x4 oacc[2][4];
  #pragma unroll
  for (int qb = 0; qb < 2; qb++)
    #pragma unroll
    for (int dt = 0; dt < 4; dt++) oacc[qb][dt] = (f32x4){0.f, 0.f, 0.f, 0.f};
  float l_i[2] = {0.f, 0.f};

  const float SCL2 = 0.125f * 1.44269504f;   // scale * log2(e)
  const float FIXM = 16.0f;                  // fixed max (power-of-2-exact shift)

  int cur = 0;
  stage(0, tstart);

  for (int j = tstart; j < bend; j++) {
    __syncthreads();                        // staged tile j visible
    if (j + 1 < bend) stage(cur ^ 1, j + 1);

    if (j < my_end) {
      const unsigned short* KsB = &Ks[cur][0];
      const unsigned short* VsB = &Vs[cur][0];
      const int kv0 = j * 64;

      bf16x8 aK[4][2];
      #pragma unroll
      for (int nt = 0; nt < 4; nt++) {
        const int row = nt * 16 + lr;
        #pragma unroll
        for (int kh = 0; kh < 2; kh++) {
          const int sc = (kh * 4 + quad) ^ (row & 7);
          aK[nt][kh] = *(const bf16x8*)&KsB[row * 64 + sc * 8];
        }
      }
      bf16x4 aV[4][4];
      #pragma unroll
      for (int dt = 0; dt < 4; dt++) {
        const int row = dt * 16 + lr;
        #pragma unroll
        for (int ks = 0; ks < 4; ks++) {
          const int sc = (ks * 2 + (quad >> 1)) ^ (row & 7);
          aV[dt][ks] = *(const bf16x4*)&VsB[row * 64 + sc * 8 + (quad & 1) * 4];
        }
      }

      f32x4 sacc[2][4];
      #pragma unroll
      for (int nt = 0; nt < 4; nt++) {
        #pragma unroll
        for (int qb = 0; qb < 2; qb++) {
          f32x4 c = (f32x4){0.f, 0.f, 0.f, 0.f};
          c = __builtin_amdgcn_mfma_f32_16x16x32_bf16(aK[nt][0], bQ[qb][0], c, 0, 0, 0);
          c = __builtin_amdgcn_mfma_f32_16x16x32_bf16(aK[nt][1], bQ[qb][1], c, 0, 0, 0);
          sacc[qb][nt] = c;
        }
      }

      const bool diag = (j == my_full - 1);
      bf16x4 bP[2][4];
      #pragma unroll
      for (int qb = 0; qb < 2; qb++) {
        if (diag) {
          const int qcol = q0 + qb * 16 + lr;
          #pragma unroll
          for (int nt = 0; nt < 4; nt++)
            #pragma unroll
            for (int i = 0; i < 4; i++)
              if (kv0 + nt * 16 + quad * 4 + i > qcol) sacc[qb][nt][i] = -INFINITY;
        }
        float rs = 0.f;
        #pragma unroll
        for (int nt = 0; nt < 4; nt++) {
          float p[4];
          #pragma unroll
          for (int i = 0; i < 4; i++) {
            p[i] = __builtin_amdgcn_exp2f(fmaf(sacc[qb][nt][i], SCL2, -FIXM));
            rs += p[i];
          }
          union { unsigned u[2]; bf16x4 v; } pk;
          pk.u[0] = pack2_rtz(p[0], p[1]);
          pk.u[1] = pack2_rtz(p[2], p[3]);
          bP[qb][nt] = pk.v;
        }
        l_i[qb] += rs;
      }

      #pragma unroll
      for (int ks = 0; ks < 4; ks++)
        #pragma unroll
        for (int dt = 0; dt < 4; dt++)
          #pragma unroll
          for (int qb = 0; qb < 2; qb++)
            oacc[qb][dt] = __builtin_amdgcn_mfma_f32_16x16x16bf16_1k(
                aV[dt][ks], bP[qb][ks], oacc[qb][dt], 0, 0, 0);
    }
    cur ^= 1;
  }

  // epilogue: reduce l across quad groups (2 shfls), then write
  #pragma unroll
  for (int qb = 0; qb < 2; qb++) {
    l_i[qb] += __shfl_xor(l_i[qb], 16);
    l_i[qb] += __shfl_xor(l_i[qb], 32);
  }

  if (np == 1) {
    #pragma unroll
    for (int qb = 0; qb < 2; qb++) {
      const float invl = __builtin_amdgcn_rcpf(l_i[qb]);
      const size_t orow = (size_t)(b * T_SEQ + q0 + qb * 16 + lr) * D_MODEL + h * D_HEAD;
      #pragma unroll
      for (int dt = 0; dt < 4; dt++) {
        us4 o;
        #pragma unroll
        for (int i = 0; i < 4; i++) o[i] = f2bf(oacc[qb][dt][i] * invl);
        *(us4*)&Out[orow + dt * 16 + quad * 4] = o;
      }
    }
  } else {
    const int idx = (g < 12) ? ((qg - 16) * 2 + piece) : (64 + (qg - 48) * 3 + piece);
    const int p = bh * 112 + idx;
    #pragma unroll
    for (int qb = 0; qb < 2; qb++) {
      Lpart[(p * 2 + qb) * 64 + lane] = l_i[qb];
      #pragma unroll
      for (int dt = 0; dt < 4; dt++) {
        us4 o;
        #pragma unroll
        for (int i = 0; i < 4; i++) o[i] = f2bf(oacc[qb][dt][i]);
        *(us4*)&Opart[(size_t)(((p * 8 + qb * 4 + dt) * 64) + lane) * 4] = o;
      }
    }
  }
}

// ---------------------------------------------------------------------------
// Merge split partials per (bh, qg>=16): O = (sum O_s) / (sum l_s).
// qgr<32 (qg 16-47): 2 slots; qgr>=32 (qg 48-63): 3 slots.
// ---------------------------------------------------------------------------
__global__ __launch_bounds__(64) void flash_reduce(
    const unsigned short* __restrict__ Opart, const float* __restrict__ Lpart,
    unsigned short* __restrict__ Out)
{
  const int bh  = blockIdx.x;
  const int qgr = blockIdx.y;          // qg = 16 + qgr
  const int q0  = (16 + qgr) * 32;
  const int b   = bh >> 4;
  const int h   = bh & 15;
  const int lane = threadIdx.x;
  const int lr   = lane & 15;
  const int quad = lane >> 4;

  int base, n;
  if (qgr < 32) { base = qgr * 2;             n = 2; }
  else          { base = 64 + (qgr - 32) * 3; n = 3; }
  base += bh * 112;

  #pragma unroll
  for (int qb = 0; qb < 2; qb++) {
    float L = 0.f;
    for (int s = 0; s < n; s++) L += Lpart[((base + s) * 2 + qb) * 64 + lane];
    const float invL = __builtin_amdgcn_rcpf(L);
    const size_t orow = (size_t)(b * T_SEQ + q0 + qb * 16 + lr) * D_MODEL + h * D_HEAD;
    #pragma unroll
    for (int dt = 0; dt < 4; dt++) {
      float acc[4] = {0.f, 0.f, 0.f, 0.f};
      for (int s = 0; s < n; s++) {
        us4 ov = *(const us4*)&Opart[(size_t)((((base + s) * 8 + qb * 4 + dt) * 64) + lane) * 4];
        #pragma unroll
        for (int i = 0; i < 4; i++) acc[i] += bf2f(ov[i]);
      }
      us4 o;
      #pragma unroll
      for (int i = 0; i < 4; i++) o[i] = f2bf(acc[i] * invL);
      *(us4*)&Out[orow + dt * 16 + quad * 4] = o;
    }
  }
}

// ---------------------------------------------------------------------------
extern "C" void kernel_launch(void* const* d_in, const int* in_sizes, int n_in,
                              void* d_out, int out_size, void* d_ws, size_t ws_size,
                              hipStream_t stream) {
  (void)in_sizes; (void)n_in; (void)out_size; (void)ws_size;

  const float* x  = (const float*)d_in[0];
  const float* wq = (const float*)d_in[1];
  const float* bq = (const float*)d_in[2];
  const float* wk = (const float*)d_in[3];
  const float* bk = (const float*)d_in[4];
  const float* wv = (const float*)d_in[5];
  const float* bv = (const float*)d_in[6];
  const float* wo = (const float*)d_in[7];
  const float* bo = (const float*)d_in[8];
  float* out = (float*)d_out;

  const int M = B_SZ * T_SEQ;   // 4096
  const int N = D_MODEL;        // 1024
  const int K = D_MODEL;        // 1024
  const size_t MN = (size_t)M * N;     // 4M elems
  const size_t WN = (size_t)N * N;     // 1M elems

  // ws layout (bf16 elems): ~50 MiB total
  unsigned short* wt    = (unsigned short*)d_ws;   // [wo,wq,wk,wv]    8 MiB
  unsigned short* xb    = wt + 4 * WN;             // [M,K]            8 MiB
  unsigned short* qkv   = xb + MN;                 // q,k [bh,T,64]   16 MiB
  unsigned short* qb    = qkv;
  unsigned short* kb    = qkv + MN;
  unsigned short* vT    = qkv + 2 * MN;            // [bh,64,T]        8 MiB
  unsigned short* attnb = vT + MN;                 // [M,N]            8 MiB
  float* Lpart = (float*)(attnb + MN);             // 3584*128 f32  1.75 MiB
  // Opart overlays [wq,wk,wv]+xb (dead after qkv_gemm): 3584 slots * 4 KB = 14 MiB
  unsigned short* Opart = wt + WN;

  conv_all<<<dim3(32, 32, 8), dim3(256), 0, stream>>>(x, wq, wk, wv, wo, wt, xb);

  qkv_gemm<<<dim3(M / 128, 48), dim3(256), 0, stream>>>(xb, wt + WN, bq, bk, bv, qkv, vT);

  flash_part<<<dim3(B_SZ * N_HEADS, 32), dim3(256), 0, stream>>>(
      qb, kb, vT, attnb, Opart, Lpart);
  flash_reduce<<<dim3(B_SZ * N_HEADS, 48), dim3(64), 0, stream>>>(
      Opart, Lpart, attnb);

  mfma_gemm<<<dim3(M / 128, N / 64), dim3(256), 0, stream>>>(attnb, wt, bo, out, M, N, K);
}